// Round 1
// baseline (1986.898 us; speedup 1.0000x reference)
//
#include <hip/hip_runtime.h>

#define EPS 1e-5f

// ---- workspace layout (float offsets) ----
#define XT_OFF    0u                         // 256*1024
#define PRE1_OFF  262144u                    // 3136*1024
#define PRE2_OFF  (PRE1_OFF + 3211264u)      // 4608*1024
#define PRE3_OFF  (PRE2_OFF + 4718592u)      // 6400*1024
#define STATS_OFF (PRE3_OFF + 6553600u)      // 224 floats: s1(32) s2(64) s3(128)
#define PARAM_OFF (STATS_OFF + 224u)         // 224 floats: a1(16) c1(16) a2(32) c2(32) a3(64) c3(64)

// ---------------- transpose x (1024,256) -> xT (256,1024) ----------------
__global__ void k_transpose(const float* __restrict__ x, float* __restrict__ xT) {
    __shared__ float tile[16][17];
    int tx = threadIdx.x, ty = threadIdx.y;
    int p0 = blockIdx.x * 16, b0 = blockIdx.y * 16;
    tile[ty][tx] = x[(b0 + ty) * 256 + p0 + tx];
    __syncthreads();
    xT[(p0 + ty) * 1024 + b0 + tx] = tile[tx][ty];
}

// ---------------- LC1: xT -> pre1 [(o*196+p)][b], stats1 ----------------
__global__ __launch_bounds__(256) void k_lc1(const float* __restrict__ xT,
                                             const float* __restrict__ W1,
                                             const float* __restrict__ b1,
                                             float* __restrict__ pre1,
                                             float* __restrict__ stats) {
    int p = blockIdx.x;              // 0..195
    int i = p / 14, j = p % 14;
    int tid = threadIdx.x;
    int b = blockIdx.y * 256 + tid;
    __shared__ float wS[144], bS[16];
    if (tid < 144) { int o = tid / 9, k = tid % 9; wS[tid] = W1[(o * 196 + p) * 9 + k]; }
    if (tid < 16) bS[tid] = b1[tid * 196 + p];
    __syncthreads();
    float xv[9];
#pragma unroll
    for (int di = 0; di < 3; di++)
#pragma unroll
        for (int dj = 0; dj < 3; dj++)
            xv[di * 3 + dj] = xT[((i + di) * 16 + (j + dj)) * 1024 + b];
    int lane = tid & 63;
#pragma unroll
    for (int o = 0; o < 16; o++) {
        float acc = bS[o];
#pragma unroll
        for (int k = 0; k < 9; k++) acc += wS[o * 9 + k] * xv[k];
        pre1[(o * 196 + p) * 1024 + b] = acc;
        float s = acc, q = acc * acc;
#pragma unroll
        for (int d = 32; d; d >>= 1) { s += __shfl_down(s, d); q += __shfl_down(q, d); }
        if (lane == 0) { atomicAdd(&stats[2 * o], s); atomicAdd(&stats[2 * o + 1], q); }
    }
}

// ---------------- finalize BN params: stats -> a,c ----------------
__global__ void k_finalize(const float* __restrict__ stats, const float* __restrict__ g,
                           const float* __restrict__ be, float* __restrict__ a,
                           float* __restrict__ c, int nch, float invN) {
    int o = threadIdx.x;
    if (o < nch) {
        float m = stats[2 * o] * invN;
        float v = stats[2 * o + 1] * invN - m * m;
        float r = rsqrtf(v + EPS);
        float av = g[o] * r;
        a[o] = av;
        c[o] = be[o] - m * av;
    }
}

// ---------------- LC2: pre1 (+BN1/ReLU inline) -> pre2, stats2 ----------------
// grid (144 p, 2 b-chunks of 512); thread tile: 32 o x 2 b
__global__ __launch_bounds__(256) void k_lc2(const float* __restrict__ pre1,
                                             const float* __restrict__ W2,
                                             const float* __restrict__ b2,
                                             const float* __restrict__ ab1,  // a1(16),c1(16)
                                             float* __restrict__ pre2,
                                             float* __restrict__ stats) {
    int p = blockIdx.x;              // 0..143
    int i = p / 12, j = p % 12;
    int tid = threadIdx.x;
    int b0 = blockIdx.y * 512 + tid * 2;
    __shared__ float wS[144 * 36];   // row (c*9+k), 36-stride (16B-aligned rows)
    __shared__ float bS[32], aS[16], cS[16];
    for (int idx = tid; idx < 4608; idx += 256) {
        int oo = idx / 144, rem = idx % 144;
        int c = rem / 9, k = rem % 9;
        wS[rem * 36 + oo] = W2[((oo * 16 + c) * 144 + p) * 9 + k];
    }
    if (tid < 32) bS[tid] = b2[tid * 144 + p];
    if (tid < 16) { aS[tid] = ab1[tid]; cS[tid] = ab1[16 + tid]; }
    __syncthreads();
    float acc0[32], acc1[32];
#pragma unroll
    for (int o = 0; o < 32; o++) { float bv = bS[o]; acc0[o] = bv; acc1[o] = bv; }
    for (int c = 0; c < 16; c++) {
        float ac = aS[c], cc = cS[c];
        float2 xv[9];
#pragma unroll
        for (int di = 0; di < 3; di++)
#pragma unroll
            for (int dj = 0; dj < 3; dj++) {
                const float2* src = (const float2*)(pre1 + (c * 196 + (i + di) * 14 + (j + dj)) * 1024);
                float2 v = src[b0 >> 1];
                v.x = fmaxf(fmaf(ac, v.x, cc), 0.f);
                v.y = fmaxf(fmaf(ac, v.y, cc), 0.f);
                xv[di * 3 + dj] = v;
            }
#pragma unroll
        for (int k = 0; k < 9; k++) {
            const float4* wrow = (const float4*)(wS + (c * 9 + k) * 36);
            float2 v = xv[k];
#pragma unroll
            for (int o4 = 0; o4 < 8; o4++) {
                float4 w = wrow[o4];
                acc0[o4 * 4 + 0] += w.x * v.x; acc1[o4 * 4 + 0] += w.x * v.y;
                acc0[o4 * 4 + 1] += w.y * v.x; acc1[o4 * 4 + 1] += w.y * v.y;
                acc0[o4 * 4 + 2] += w.z * v.x; acc1[o4 * 4 + 2] += w.z * v.y;
                acc0[o4 * 4 + 3] += w.w * v.x; acc1[o4 * 4 + 3] += w.w * v.y;
            }
        }
    }
    int lane = tid & 63;
#pragma unroll
    for (int o = 0; o < 32; o++) {
        float2* dst = (float2*)(pre2 + (o * 144 + p) * 1024);
        dst[b0 >> 1] = make_float2(acc0[o], acc1[o]);
        float s = acc0[o] + acc1[o];
        float q = acc0[o] * acc0[o] + acc1[o] * acc1[o];
#pragma unroll
        for (int d = 32; d; d >>= 1) { s += __shfl_down(s, d); q += __shfl_down(q, d); }
        if (lane == 0) { atomicAdd(&stats[2 * o], s); atomicAdd(&stats[2 * o + 1], q); }
    }
}

// ---------------- LC3: pre2 (+BN2/ReLU inline) -> pre3, stats3 ----------------
// grid (100 p, 2 b-chunks of 512, 2 o-halves); thread tile: 32 o x 2 b
__global__ __launch_bounds__(256) void k_lc3(const float* __restrict__ pre2,
                                             const float* __restrict__ W3,
                                             const float* __restrict__ b3,
                                             const float* __restrict__ ab2,  // a2(32),c2(32)
                                             float* __restrict__ pre3,
                                             float* __restrict__ stats) {
    int p = blockIdx.x;              // 0..99
    int i = p / 10, j = p % 10;
    int tid = threadIdx.x;
    int b0 = blockIdx.y * 512 + tid * 2;
    int obase = blockIdx.z * 32;
    __shared__ float wS[288 * 36];   // 41.5 KB
    __shared__ float bS[32], aS[32], cS[32];
    for (int idx = tid; idx < 9216; idx += 256) {
        int oo = idx / 288, rem = idx % 288;
        int c = rem / 9, k = rem % 9;
        wS[rem * 36 + oo] = W3[(((obase + oo) * 32 + c) * 100 + p) * 9 + k];
    }
    if (tid < 32) { bS[tid] = b3[(obase + tid) * 100 + p]; aS[tid] = ab2[tid]; cS[tid] = ab2[32 + tid]; }
    __syncthreads();
    float acc0[32], acc1[32];
#pragma unroll
    for (int o = 0; o < 32; o++) { float bv = bS[o]; acc0[o] = bv; acc1[o] = bv; }
    for (int c = 0; c < 32; c++) {
        float ac = aS[c], cc = cS[c];
        float2 xv[9];
#pragma unroll
        for (int di = 0; di < 3; di++)
#pragma unroll
            for (int dj = 0; dj < 3; dj++) {
                const float2* src = (const float2*)(pre2 + (c * 144 + (i + di) * 12 + (j + dj)) * 1024);
                float2 v = src[b0 >> 1];
                v.x = fmaxf(fmaf(ac, v.x, cc), 0.f);
                v.y = fmaxf(fmaf(ac, v.y, cc), 0.f);
                xv[di * 3 + dj] = v;
            }
#pragma unroll
        for (int k = 0; k < 9; k++) {
            const float4* wrow = (const float4*)(wS + (c * 9 + k) * 36);
            float2 v = xv[k];
#pragma unroll
            for (int o4 = 0; o4 < 8; o4++) {
                float4 w = wrow[o4];
                acc0[o4 * 4 + 0] += w.x * v.x; acc1[o4 * 4 + 0] += w.x * v.y;
                acc0[o4 * 4 + 1] += w.y * v.x; acc1[o4 * 4 + 1] += w.y * v.y;
                acc0[o4 * 4 + 2] += w.z * v.x; acc1[o4 * 4 + 2] += w.z * v.y;
                acc0[o4 * 4 + 3] += w.w * v.x; acc1[o4 * 4 + 3] += w.w * v.y;
            }
        }
    }
    int lane = tid & 63;
#pragma unroll
    for (int o = 0; o < 32; o++) {
        float2* dst = (float2*)(pre3 + ((obase + o) * 100 + p) * 1024);
        dst[b0 >> 1] = make_float2(acc0[o], acc1[o]);
        float s = acc0[o] + acc1[o];
        float q = acc0[o] * acc0[o] + acc1[o] * acc1[o];
#pragma unroll
        for (int d = 32; d; d >>= 1) { s += __shfl_down(s, d); q += __shfl_down(q, d); }
        if (lane == 0) { atomicAdd(&stats[2 * (obase + o)], s); atomicAdd(&stats[2 * (obase + o) + 1], q); }
    }
}

// ---------------- out init: out[b][j] = fcb[j] ----------------
__global__ __launch_bounds__(256) void k_init_out(const float* __restrict__ fcb, float* __restrict__ out) {
    int idx = blockIdx.x * 256 + threadIdx.x;
    if (idx < 10240) out[idx] = fcb[idx % 10];
}

// ---------------- FC: tanh(BN3(pre3)) @ fcW^T, atomic accumulate ----------------
// grid (4 b-chunks, 64 f-chunks); f-chunk fc == channel o (100 f's each)
__global__ __launch_bounds__(256) void k_fc(const float* __restrict__ pre3,
                                            const float* __restrict__ fcW,
                                            const float* __restrict__ ab3,  // a3(64),c3(64)
                                            float* __restrict__ out) {
    int fchunk = blockIdx.y;         // == channel o
    int f0 = fchunk * 100;
    int tid = threadIdx.x;
    int b = blockIdx.x * 256 + tid;
    __shared__ float wS[1000];
    for (int idx = tid; idx < 1000; idx += 256) {
        int fi = idx / 10, jj = idx % 10;
        wS[idx] = fcW[jj * 6400 + f0 + fi];
    }
    __syncthreads();
    float ao = ab3[fchunk], co = ab3[64 + fchunk];
    float acc[10];
#pragma unroll
    for (int jj = 0; jj < 10; jj++) acc[jj] = 0.f;
    for (int fi = 0; fi < 100; fi++) {
        float v = pre3[(f0 + fi) * 1024 + b];
        v = fmaf(ao, v, co);
        float e = __expf(2.f * v);
        v = 1.f - 2.f / (e + 1.f);   // tanh, safe at +/-inf
#pragma unroll
        for (int jj = 0; jj < 10; jj++) acc[jj] += wS[fi * 10 + jj] * v;
    }
#pragma unroll
    for (int jj = 0; jj < 10; jj++) atomicAdd(&out[b * 10 + jj], acc[jj]);
}

extern "C" void kernel_launch(void* const* d_in, const int* in_sizes, int n_in,
                              void* d_out, int out_size, void* d_ws, size_t ws_size,
                              hipStream_t stream) {
    const float* x   = (const float*)d_in[0];
    const float* W1  = (const float*)d_in[1];
    const float* b1  = (const float*)d_in[2];
    const float* g1  = (const float*)d_in[3];
    const float* be1 = (const float*)d_in[4];
    const float* W2  = (const float*)d_in[5];
    const float* b2  = (const float*)d_in[6];
    const float* g2  = (const float*)d_in[7];
    const float* be2 = (const float*)d_in[8];
    const float* W3  = (const float*)d_in[9];
    const float* b3  = (const float*)d_in[10];
    const float* g3  = (const float*)d_in[11];
    const float* be3 = (const float*)d_in[12];
    const float* fcW = (const float*)d_in[13];
    const float* fcb = (const float*)d_in[14];
    float* out = (float*)d_out;
    float* ws = (float*)d_ws;

    float* xT   = ws + XT_OFF;
    float* pre1 = ws + PRE1_OFF;
    float* pre2 = ws + PRE2_OFF;
    float* pre3 = ws + PRE3_OFF;
    float* st   = ws + STATS_OFF;
    float* prm  = ws + PARAM_OFF;

    hipMemsetAsync(st, 0, 224 * sizeof(float), stream);

    k_transpose<<<dim3(16, 64), dim3(16, 16), 0, stream>>>(x, xT);
    k_lc1<<<dim3(196, 4), 256, 0, stream>>>(xT, W1, b1, pre1, st);
    k_finalize<<<1, 64, 0, stream>>>(st, g1, be1, prm, prm + 16, 16, 1.f / (1024.f * 196.f));
    k_lc2<<<dim3(144, 2), 256, 0, stream>>>(pre1, W2, b2, prm, pre2, st + 32);
    k_finalize<<<1, 64, 0, stream>>>(st + 32, g2, be2, prm + 32, prm + 64, 32, 1.f / (1024.f * 144.f));
    k_lc3<<<dim3(100, 2, 2), 256, 0, stream>>>(pre2, W3, b3, prm + 32, pre3, st + 96);
    k_finalize<<<1, 64, 0, stream>>>(st + 96, g3, be3, prm + 96, prm + 160, 64, 1.f / (1024.f * 100.f));
    k_init_out<<<40, 256, 0, stream>>>(fcb, out);
    k_fc<<<dim3(4, 64), 256, 0, stream>>>(pre3, fcW, prm + 96, out);
}

// Round 2
// 278.627 us; speedup vs baseline: 7.1310x; 7.1310x over previous
//
#include <hip/hip_runtime.h>

#define EPS 1e-5f

// ---- workspace layout (float offsets) ----
#define XT_OFF    0u                         // 256*1024 (xT; dead after lc1)
#define PRE1_OFF  262144u                    // 3136*1024 (pre1; dead after lc2)
#define PRE2_OFF  (PRE1_OFF + 3211264u)      // 4608*1024 (pre2; dead after lc3)
#define PRE3_OFF  (PRE2_OFF + 4718592u)      // 6400*1024
#define PARAM_OFF (PRE3_OFF + 6553600u)      // 224 floats: a1(16) c1(16) a2(32) c2(32) a3(64) c3(64)
#define P1_OFF    (PARAM_OFF + 224u)         // 32*3136 per-wave stats partials (lc1)
#define P2_OFF    XT_OFF                     // 64*1152 partials (lc2), aliases dead xT
#define P3_OFF    PRE1_OFF                   // 128*800 partials (lc3), aliases dead pre1
#define FP_OFF    (PRE1_OFF + 262144u)       // 64*10240 fc partials, aliases dead pre1 tail

// ---------------- transpose x (1024,256) -> xT (256,1024) ----------------
__global__ void k_transpose(const float* __restrict__ x, float* __restrict__ xT) {
    __shared__ float tile[16][17];
    int tx = threadIdx.x, ty = threadIdx.y;
    int p0 = blockIdx.x * 16, b0 = blockIdx.y * 16;
    tile[ty][tx] = x[(b0 + ty) * 256 + p0 + tx];
    __syncthreads();
    xT[(p0 + ty) * 1024 + b0 + tx] = tile[tx][ty];
}

// ---------------- LC1: xT -> pre1 [(o*196+p)][b], per-wave stat partials ----------------
__global__ __launch_bounds__(256) void k_lc1(const float* __restrict__ xT,
                                             const float* __restrict__ W1,
                                             const float* __restrict__ b1,
                                             float* __restrict__ pre1,
                                             float* __restrict__ part) {  // [2*ch][3136]
    int p = blockIdx.x;              // 0..195
    int i = p / 14, j = p % 14;
    int tid = threadIdx.x;
    int b = blockIdx.y * 256 + tid;
    __shared__ float wS[144], bS[16];
    if (tid < 144) { int o = tid / 9, k = tid % 9; wS[tid] = W1[(o * 196 + p) * 9 + k]; }
    if (tid < 16) bS[tid] = b1[tid * 196 + p];
    __syncthreads();
    float xv[9];
#pragma unroll
    for (int di = 0; di < 3; di++)
#pragma unroll
        for (int dj = 0; dj < 3; dj++)
            xv[di * 3 + dj] = xT[((i + di) * 16 + (j + dj)) * 1024 + b];
    int lane = tid & 63;
    int w = (blockIdx.y * 196 + blockIdx.x) * 4 + (tid >> 6);
#pragma unroll
    for (int o = 0; o < 16; o++) {
        float acc = bS[o];
#pragma unroll
        for (int k = 0; k < 9; k++) acc += wS[o * 9 + k] * xv[k];
        pre1[(o * 196 + p) * 1024 + b] = acc;
        float s = acc, q = acc * acc;
#pragma unroll
        for (int d = 32; d; d >>= 1) { s += __shfl_down(s, d); q += __shfl_down(q, d); }
        if (lane == 0) { part[(2 * o) * 3136 + w] = s; part[(2 * o + 1) * 3136 + w] = q; }
    }
}

// ---------------- reduce per-wave partials -> BN (a,c), fused finalize ----------------
// grid = nch blocks; part layout [2*ch][nwaves]
__global__ __launch_bounds__(256) void k_stats(const float* __restrict__ part, int nwaves,
                                               const float* __restrict__ g,
                                               const float* __restrict__ be,
                                               float* __restrict__ a, float* __restrict__ c,
                                               float invN) {
    int ch = blockIdx.x;
    int tid = threadIdx.x;
    const float* ps = part + (size_t)(2 * ch) * nwaves;
    const float* pq = part + (size_t)(2 * ch + 1) * nwaves;
    float s = 0.f, q = 0.f;
    for (int w = tid; w < nwaves; w += 256) { s += ps[w]; q += pq[w]; }
#pragma unroll
    for (int d = 32; d; d >>= 1) { s += __shfl_down(s, d); q += __shfl_down(q, d); }
    __shared__ float sS[4], qS[4];
    if ((tid & 63) == 0) { sS[tid >> 6] = s; qS[tid >> 6] = q; }
    __syncthreads();
    if (tid == 0) {
        s = sS[0] + sS[1] + sS[2] + sS[3];
        q = qS[0] + qS[1] + qS[2] + qS[3];
        float m = s * invN;
        float v = q * invN - m * m;
        float r = rsqrtf(v + EPS);
        float av = g[ch] * r;
        a[ch] = av;
        c[ch] = be[ch] - m * av;
    }
}

// ---------------- LC2: pre1 (+BN1/ReLU inline) -> pre2, stat partials ----------------
// grid (144 p, 2 b-chunks of 512); thread tile: 32 o x 2 b
__global__ __launch_bounds__(256) void k_lc2(const float* __restrict__ pre1,
                                             const float* __restrict__ W2,
                                             const float* __restrict__ b2,
                                             const float* __restrict__ ab1,  // a1(16),c1(16)
                                             float* __restrict__ pre2,
                                             float* __restrict__ part) {  // [2*ch][1152]
    int p = blockIdx.x;              // 0..143
    int i = p / 12, j = p % 12;
    int tid = threadIdx.x;
    int b0 = blockIdx.y * 512 + tid * 2;
    __shared__ float wS[144 * 36];   // row (c*9+k), 36-stride (16B-aligned rows)
    __shared__ float bS[32], aS[16], cS[16];
    for (int idx = tid; idx < 4608; idx += 256) {
        int oo = idx / 144, rem = idx % 144;
        int c = rem / 9, k = rem % 9;
        wS[rem * 36 + oo] = W2[((oo * 16 + c) * 144 + p) * 9 + k];
    }
    if (tid < 32) bS[tid] = b2[tid * 144 + p];
    if (tid < 16) { aS[tid] = ab1[tid]; cS[tid] = ab1[16 + tid]; }
    __syncthreads();
    float acc0[32], acc1[32];
#pragma unroll
    for (int o = 0; o < 32; o++) { float bv = bS[o]; acc0[o] = bv; acc1[o] = bv; }
    for (int c = 0; c < 16; c++) {
        float ac = aS[c], cc = cS[c];
        float2 xv[9];
#pragma unroll
        for (int di = 0; di < 3; di++)
#pragma unroll
            for (int dj = 0; dj < 3; dj++) {
                const float2* src = (const float2*)(pre1 + (c * 196 + (i + di) * 14 + (j + dj)) * 1024);
                float2 v = src[b0 >> 1];
                v.x = fmaxf(fmaf(ac, v.x, cc), 0.f);
                v.y = fmaxf(fmaf(ac, v.y, cc), 0.f);
                xv[di * 3 + dj] = v;
            }
#pragma unroll
        for (int k = 0; k < 9; k++) {
            const float4* wrow = (const float4*)(wS + (c * 9 + k) * 36);
            float2 v = xv[k];
#pragma unroll
            for (int o4 = 0; o4 < 8; o4++) {
                float4 w = wrow[o4];
                acc0[o4 * 4 + 0] += w.x * v.x; acc1[o4 * 4 + 0] += w.x * v.y;
                acc0[o4 * 4 + 1] += w.y * v.x; acc1[o4 * 4 + 1] += w.y * v.y;
                acc0[o4 * 4 + 2] += w.z * v.x; acc1[o4 * 4 + 2] += w.z * v.y;
                acc0[o4 * 4 + 3] += w.w * v.x; acc1[o4 * 4 + 3] += w.w * v.y;
            }
        }
    }
    int lane = tid & 63;
    int w = (blockIdx.y * 144 + blockIdx.x) * 4 + (tid >> 6);
#pragma unroll
    for (int o = 0; o < 32; o++) {
        float2* dst = (float2*)(pre2 + (o * 144 + p) * 1024);
        dst[b0 >> 1] = make_float2(acc0[o], acc1[o]);
        float s = acc0[o] + acc1[o];
        float q = acc0[o] * acc0[o] + acc1[o] * acc1[o];
#pragma unroll
        for (int d = 32; d; d >>= 1) { s += __shfl_down(s, d); q += __shfl_down(q, d); }
        if (lane == 0) { part[(2 * o) * 1152 + w] = s; part[(2 * o + 1) * 1152 + w] = q; }
    }
}

// ---------------- LC3: pre2 (+BN2/ReLU inline) -> pre3, stat partials ----------------
// grid (100 p, 2 b-chunks of 512, 2 o-halves); thread tile: 32 o x 2 b
__global__ __launch_bounds__(256) void k_lc3(const float* __restrict__ pre2,
                                             const float* __restrict__ W3,
                                             const float* __restrict__ b3,
                                             const float* __restrict__ ab2,  // a2(32),c2(32)
                                             float* __restrict__ pre3,
                                             float* __restrict__ part) {  // [2*ch][800]
    int p = blockIdx.x;              // 0..99
    int i = p / 10, j = p % 10;
    int tid = threadIdx.x;
    int b0 = blockIdx.y * 512 + tid * 2;
    int obase = blockIdx.z * 32;
    __shared__ float wS[288 * 36];   // 41.5 KB
    __shared__ float bS[32], aS[32], cS[32];
    for (int idx = tid; idx < 9216; idx += 256) {
        int oo = idx / 288, rem = idx % 288;
        int c = rem / 9, k = rem % 9;
        wS[rem * 36 + oo] = W3[(((obase + oo) * 32 + c) * 100 + p) * 9 + k];
    }
    if (tid < 32) { bS[tid] = b3[(obase + tid) * 100 + p]; aS[tid] = ab2[tid]; cS[tid] = ab2[32 + tid]; }
    __syncthreads();
    float acc0[32], acc1[32];
#pragma unroll
    for (int o = 0; o < 32; o++) { float bv = bS[o]; acc0[o] = bv; acc1[o] = bv; }
    for (int c = 0; c < 32; c++) {
        float ac = aS[c], cc = cS[c];
        float2 xv[9];
#pragma unroll
        for (int di = 0; di < 3; di++)
#pragma unroll
            for (int dj = 0; dj < 3; dj++) {
                const float2* src = (const float2*)(pre2 + (c * 144 + (i + di) * 12 + (j + dj)) * 1024);
                float2 v = src[b0 >> 1];
                v.x = fmaxf(fmaf(ac, v.x, cc), 0.f);
                v.y = fmaxf(fmaf(ac, v.y, cc), 0.f);
                xv[di * 3 + dj] = v;
            }
#pragma unroll
        for (int k = 0; k < 9; k++) {
            const float4* wrow = (const float4*)(wS + (c * 9 + k) * 36);
            float2 v = xv[k];
#pragma unroll
            for (int o4 = 0; o4 < 8; o4++) {
                float4 w = wrow[o4];
                acc0[o4 * 4 + 0] += w.x * v.x; acc1[o4 * 4 + 0] += w.x * v.y;
                acc0[o4 * 4 + 1] += w.y * v.x; acc1[o4 * 4 + 1] += w.y * v.y;
                acc0[o4 * 4 + 2] += w.z * v.x; acc1[o4 * 4 + 2] += w.z * v.y;
                acc0[o4 * 4 + 3] += w.w * v.x; acc1[o4 * 4 + 3] += w.w * v.y;
            }
        }
    }
    int lane = tid & 63;
    int w = (blockIdx.y * 100 + blockIdx.x) * 4 + (tid >> 6);  // 0..799 per channel
#pragma unroll
    for (int o = 0; o < 32; o++) {
        float2* dst = (float2*)(pre3 + ((obase + o) * 100 + p) * 1024);
        dst[b0 >> 1] = make_float2(acc0[o], acc1[o]);
        float s = acc0[o] + acc1[o];
        float q = acc0[o] * acc0[o] + acc1[o] * acc1[o];
#pragma unroll
        for (int d = 32; d; d >>= 1) { s += __shfl_down(s, d); q += __shfl_down(q, d); }
        int ch = obase + o;
        if (lane == 0) { part[(2 * ch) * 800 + w] = s; part[(2 * ch + 1) * 800 + w] = q; }
    }
}

// ---------------- FC: tanh(BN3(pre3)) @ fcW^T -> partials [fc][jj][b] ----------------
// grid (4 b-chunks, 64 f-chunks); f-chunk fc == channel o (100 f's each)
__global__ __launch_bounds__(256) void k_fc(const float* __restrict__ pre3,
                                            const float* __restrict__ fcW,
                                            const float* __restrict__ ab3,  // a3(64),c3(64)
                                            float* __restrict__ fpart) {
    int fchunk = blockIdx.y;         // == channel o
    int f0 = fchunk * 100;
    int tid = threadIdx.x;
    int b = blockIdx.x * 256 + tid;
    __shared__ float wS[1000];
    for (int idx = tid; idx < 1000; idx += 256) {
        int fi = idx / 10, jj = idx % 10;
        wS[idx] = fcW[jj * 6400 + f0 + fi];
    }
    __syncthreads();
    float ao = ab3[fchunk], co = ab3[64 + fchunk];
    float acc[10];
#pragma unroll
    for (int jj = 0; jj < 10; jj++) acc[jj] = 0.f;
    for (int fi = 0; fi < 100; fi++) {
        float v = pre3[(f0 + fi) * 1024 + b];
        v = fmaf(ao, v, co);
        float e = __expf(2.f * v);
        v = 1.f - 2.f / (e + 1.f);   // tanh, safe at +/-inf
#pragma unroll
        for (int jj = 0; jj < 10; jj++) acc[jj] += wS[fi * 10 + jj] * v;
    }
#pragma unroll
    for (int jj = 0; jj < 10; jj++) fpart[fchunk * 10240 + jj * 1024 + b] = acc[jj];
}

// ---------------- reduce fc partials + bias -> out ----------------
__global__ __launch_bounds__(256) void k_fc_reduce(const float* __restrict__ fpart,
                                                   const float* __restrict__ fcb,
                                                   float* __restrict__ out) {
    int idx = blockIdx.x * 256 + threadIdx.x;  // jj*1024 + b
    int jj = idx >> 10, b = idx & 1023;
    float acc = fcb[jj];
    for (int fc = 0; fc < 64; fc++) acc += fpart[fc * 10240 + idx];
    out[b * 10 + jj] = acc;
}

extern "C" void kernel_launch(void* const* d_in, const int* in_sizes, int n_in,
                              void* d_out, int out_size, void* d_ws, size_t ws_size,
                              hipStream_t stream) {
    const float* x   = (const float*)d_in[0];
    const float* W1  = (const float*)d_in[1];
    const float* b1  = (const float*)d_in[2];
    const float* g1  = (const float*)d_in[3];
    const float* be1 = (const float*)d_in[4];
    const float* W2  = (const float*)d_in[5];
    const float* b2  = (const float*)d_in[6];
    const float* g2  = (const float*)d_in[7];
    const float* be2 = (const float*)d_in[8];
    const float* W3  = (const float*)d_in[9];
    const float* b3  = (const float*)d_in[10];
    const float* g3  = (const float*)d_in[11];
    const float* be3 = (const float*)d_in[12];
    const float* fcW = (const float*)d_in[13];
    const float* fcb = (const float*)d_in[14];
    float* out = (float*)d_out;
    float* ws = (float*)d_ws;

    float* xT   = ws + XT_OFF;
    float* pre1 = ws + PRE1_OFF;
    float* pre2 = ws + PRE2_OFF;
    float* pre3 = ws + PRE3_OFF;
    float* prm  = ws + PARAM_OFF;
    float* p1   = ws + P1_OFF;
    float* p2   = ws + P2_OFF;
    float* p3   = ws + P3_OFF;
    float* fp   = ws + FP_OFF;

    k_transpose<<<dim3(16, 64), dim3(16, 16), 0, stream>>>(x, xT);
    k_lc1<<<dim3(196, 4), 256, 0, stream>>>(xT, W1, b1, pre1, p1);
    k_stats<<<16, 256, 0, stream>>>(p1, 3136, g1, be1, prm, prm + 16, 1.f / (1024.f * 196.f));
    k_lc2<<<dim3(144, 2), 256, 0, stream>>>(pre1, W2, b2, prm, pre2, p2);
    k_stats<<<32, 256, 0, stream>>>(p2, 1152, g2, be2, prm + 32, prm + 64, 1.f / (1024.f * 144.f));
    k_lc3<<<dim3(100, 2, 2), 256, 0, stream>>>(pre2, W3, b3, prm + 32, pre3, p3);
    k_stats<<<64, 256, 0, stream>>>(p3, 800, g3, be3, prm + 96, prm + 160, 1.f / (1024.f * 100.f));
    k_fc<<<dim3(4, 64), 256, 0, stream>>>(pre3, fcW, prm + 96, fp);
    k_fc_reduce<<<40, 256, 0, stream>>>(fp, fcb, out);
}

// Round 3
// 181.273 us; speedup vs baseline: 10.9608x; 1.5371x over previous
//
#include <hip/hip_runtime.h>

#define EPS 1e-5f

typedef _Float16 f16x8 __attribute__((ext_vector_type(8)));
typedef _Float16 f16x4 __attribute__((ext_vector_type(4)));
typedef float f32x4 __attribute__((ext_vector_type(4)));

// ---- workspace layout (float offsets) ----
#define XT_OFF    0u          // 256*1024 fp32
#define ACT1_OFF  262144u     // f16 196*1024*16 = 3,211,264 halves (1,605,632 f)
#define ACT2_OFF  1867776u    // f16 144*1024*32 = 4,718,592 halves (2,359,296 f)
#define ACT3_OFF  4227072u    // f16 100*1024*64 = 6,553,600 halves (3,276,800 f)
#define W2H_OFF   7503872u    // f16 144*5*32*32 = 737,280 halves (368,640 f)
#define W3H_OFF   7872512u    // f16 100*9*64*32 = 1,843,200 halves (921,600 f)
#define P1_OFF    8794112u    // fp32 2*16*3136
#define P2_OFF    8894464u    // fp32 2*32*4608
#define P3_OFF    9189376u    // fp32 2*64*3200
#define FP_OFF    9598976u    // fp32 100*10*1024
#define PRM_OFF   10622976u   // fp32 224: a1(16) c1(16) a2(32) c2(32) a3(64) c3(64)
#define ACH_OFF   10623200u   // f16 region: ach1(32) ach2(64) ach3(128)

// ---------------- transpose x (1024,256) -> xT (256,1024) ----------------
__global__ void k_transpose(const float* __restrict__ x, float* __restrict__ xT) {
    __shared__ float tile[16][17];
    int tx = threadIdx.x, ty = threadIdx.y;
    int p0 = blockIdx.x * 16, b0 = blockIdx.y * 16;
    tile[ty][tx] = x[(b0 + ty) * 256 + p0 + tx];
    __syncthreads();
    xT[(p0 + ty) * 1024 + b0 + tx] = tile[tx][ty];
}

// ---------------- weight convert: W2 -> W2h [p][pair5][o][k32], W3 -> W3h [p][pos9][o][c32]
__global__ __launch_bounds__(256) void k_wcvt(const float* __restrict__ W2,
                                              const float* __restrict__ W3,
                                              _Float16* __restrict__ W2h,
                                              _Float16* __restrict__ W3h) {
    int idx = blockIdx.x * 256 + threadIdx.x;
    if (idx < 737280) {
        int k = idx & 31, o = (idx >> 5) & 31, rest = idx >> 10;
        int t = rest % 5, p = rest / 5;
        int pos = 2 * t + (k >> 4), c = k & 15;
        float v = (pos < 9) ? W2[((o * 16 + c) * 144 + p) * 9 + pos] : 0.f;
        W2h[idx] = (_Float16)v;
    } else {
        int jdx = idx - 737280;
        if (jdx < 1843200) {
            int c = jdx & 31, o = (jdx >> 5) & 63, rest = jdx >> 11;
            int pos = rest % 9, p = rest / 9;
            W3h[jdx] = (_Float16)W3[((o * 32 + c) * 100 + p) * 9 + pos];
        }
    }
}

// ---------------- LC1 (fp32 math): xT -> act1h f16 [p][b][c16], stat partials ----------------
__global__ __launch_bounds__(256) void k_lc1(const float* __restrict__ xT,
                                             const float* __restrict__ W1,
                                             const float* __restrict__ b1,
                                             _Float16* __restrict__ act1h,
                                             float* __restrict__ part) {  // [2*ch][3136]
    int p = blockIdx.x;              // 0..195
    int i = p / 14, j = p % 14;
    int tid = threadIdx.x;
    int b = blockIdx.y * 256 + tid;
    __shared__ float wS[144], bS[16];
    if (tid < 144) { int o = tid / 9, k = tid % 9; wS[tid] = W1[(o * 196 + p) * 9 + k]; }
    if (tid < 16) bS[tid] = b1[tid * 196 + p];
    __syncthreads();
    float xv[9];
#pragma unroll
    for (int di = 0; di < 3; di++)
#pragma unroll
        for (int dj = 0; dj < 3; dj++)
            xv[di * 3 + dj] = xT[((i + di) * 16 + (j + dj)) * 1024 + b];
    float accv[16];
#pragma unroll
    for (int o = 0; o < 16; o++) {
        float acc = bS[o];
#pragma unroll
        for (int k = 0; k < 9; k++) acc += wS[o * 9 + k] * xv[k];
        accv[o] = acc;
    }
    f16x8 lo, hi;
#pragma unroll
    for (int e = 0; e < 8; e++) { lo[e] = (_Float16)accv[e]; hi[e] = (_Float16)accv[8 + e]; }
    _Float16* dst = act1h + ((size_t)(p * 1024 + b)) * 16;
    *(f16x8*)dst = lo;
    *(f16x8*)(dst + 8) = hi;
    int lane = tid & 63;
    int w = (blockIdx.y * 196 + blockIdx.x) * 4 + (tid >> 6);
#pragma unroll
    for (int o = 0; o < 16; o++) {
        float s = accv[o], q = accv[o] * accv[o];
#pragma unroll
        for (int d = 32; d; d >>= 1) { s += __shfl_down(s, d); q += __shfl_down(q, d); }
        if (lane == 0) { part[(2 * o) * 3136 + w] = s; part[(2 * o + 1) * 3136 + w] = q; }
    }
}

// ---------------- reduce partials -> fp32 a,c and f16 table ----------------
__global__ __launch_bounds__(256) void k_stats(const float* __restrict__ part, int nwaves,
                                               const float* __restrict__ g,
                                               const float* __restrict__ be,
                                               float* __restrict__ a, float* __restrict__ c,
                                               _Float16* __restrict__ ach, int C, float invN) {
    int ch = blockIdx.x;
    int tid = threadIdx.x;
    const float* ps = part + (size_t)(2 * ch) * nwaves;
    const float* pq = part + (size_t)(2 * ch + 1) * nwaves;
    float s = 0.f, q = 0.f;
    for (int w = tid; w < nwaves; w += 256) { s += ps[w]; q += pq[w]; }
#pragma unroll
    for (int d = 32; d; d >>= 1) { s += __shfl_down(s, d); q += __shfl_down(q, d); }
    __shared__ float sS[4], qS[4];
    if ((tid & 63) == 0) { sS[tid >> 6] = s; qS[tid >> 6] = q; }
    __syncthreads();
    if (tid == 0) {
        s = sS[0] + sS[1] + sS[2] + sS[3];
        q = qS[0] + qS[1] + qS[2] + qS[3];
        float m = s * invN;
        float v = q * invN - m * m;
        float r = rsqrtf(v + EPS);
        float av = g[ch] * r;
        float cv = be[ch] - m * av;
        a[ch] = av; c[ch] = cv;
        ach[ch] = (_Float16)av; ach[C + ch] = (_Float16)cv;
    }
}

// ---------------- LC2 MFMA: act1h (+BN1/ReLU) -> act2h f16 [p][b][c32], partials ----------------
// grid (144 p, 8 bgroups of 128); wave: o32 x b32; K packed as 5 pos-pairs of 32
__global__ __launch_bounds__(256) void k_lc2m(const _Float16* __restrict__ act1h,
                                              const _Float16* __restrict__ W2h,
                                              const float* __restrict__ b2,
                                              const _Float16* __restrict__ ach1,
                                              _Float16* __restrict__ act2h,
                                              float* __restrict__ part) {  // [2*ch][4608]
    int p = blockIdx.x, i = p / 12, j = p % 12;
    int tid = threadIdx.x, wv = tid >> 6, lane = tid & 63, n = lane & 15, quad = lane >> 4;
    int bbase = blockIdx.y * 128 + wv * 32;
    f16x8 a8 = *(const f16x8*)(ach1 + (quad & 1) * 8);
    f16x8 c8 = *(const f16x8*)(ach1 + 16 + (quad & 1) * 8);
    f32x4 acc[2][2] = {};
#pragma unroll
    for (int t = 0; t < 5; t++) {
        int pos0 = 2 * t, pos1 = (2 * t + 1 < 9) ? 2 * t + 1 : 8;
        int mypos = (quad >> 1) ? pos1 : pos0;
        int ip = (i + mypos / 3) * 14 + (j + mypos % 3);
        f16x8 bfr[2];
#pragma unroll
        for (int nt = 0; nt < 2; nt++) {
            f16x8 x = *(const f16x8*)(act1h + ((size_t)(ip * 1024 + bbase + nt * 16 + n)) * 16 + (quad & 1) * 8);
#pragma unroll
            for (int e = 0; e < 8; e++) {
                _Float16 v = x[e] * a8[e] + c8[e];
                x[e] = v > (_Float16)0.f ? v : (_Float16)0.f;
            }
            bfr[nt] = x;
        }
        f16x8 afr[2];
#pragma unroll
        for (int ot = 0; ot < 2; ot++)
            afr[ot] = *(const f16x8*)(W2h + ((size_t)((p * 5 + t) * 32 + ot * 16 + n)) * 32 + quad * 8);
#pragma unroll
        for (int ot = 0; ot < 2; ot++)
#pragma unroll
            for (int nt = 0; nt < 2; nt++)
                acc[ot][nt] = __builtin_amdgcn_mfma_f32_16x16x32_f16(afr[ot], bfr[nt], acc[ot][nt], 0, 0, 0);
    }
    float s[8] = {}, q[8] = {};
#pragma unroll
    for (int ot = 0; ot < 2; ot++) {
        float bias[4];
#pragma unroll
        for (int r = 0; r < 4; r++) bias[r] = b2[(ot * 16 + quad * 4 + r) * 144 + p];
#pragma unroll
        for (int nt = 0; nt < 2; nt++) {
            int b = bbase + nt * 16 + n;
            f16x4 st;
#pragma unroll
            for (int r = 0; r < 4; r++) {
                float v = acc[ot][nt][r] + bias[r];
                st[r] = (_Float16)v;
                s[ot * 4 + r] += v; q[ot * 4 + r] += v * v;
            }
            *(f16x4*)(act2h + ((size_t)(p * 1024 + b)) * 32 + ot * 16 + quad * 4) = st;
        }
    }
    int w = (p * 8 + blockIdx.y) * 4 + wv;
#pragma unroll
    for (int u = 0; u < 8; u++) {
        float ss = s[u], qq = q[u];
#pragma unroll
        for (int d = 8; d; d >>= 1) { ss += __shfl_down(ss, d); qq += __shfl_down(qq, d); }
        if (n == 0) {
            int o = (u >> 2) * 16 + quad * 4 + (u & 3);
            part[(2 * o) * 4608 + w] = ss; part[(2 * o + 1) * 4608 + w] = qq;
        }
    }
}

// ---------------- LC3 MFMA: act2h (+BN2/ReLU) -> act3h f16 [p][b][c64], partials ----------------
// grid (100 p, 8 bgroups of 128); wave: o64 x b32; K = 9 pos x 32 c
__global__ __launch_bounds__(256) void k_lc3m(const _Float16* __restrict__ act2h,
                                              const _Float16* __restrict__ W3h,
                                              const float* __restrict__ b3,
                                              const _Float16* __restrict__ ach2,
                                              _Float16* __restrict__ act3h,
                                              float* __restrict__ part) {  // [2*ch][3200]
    int p = blockIdx.x, i = p / 10, j = p % 10;
    int tid = threadIdx.x, wv = tid >> 6, lane = tid & 63, n = lane & 15, quad = lane >> 4;
    int bbase = blockIdx.y * 128 + wv * 32;
    f16x8 a8 = *(const f16x8*)(ach2 + quad * 8);
    f16x8 c8 = *(const f16x8*)(ach2 + 32 + quad * 8);
    f32x4 acc[4][2] = {};
#pragma unroll
    for (int pos = 0; pos < 9; pos++) {
        int ip = (i + pos / 3) * 12 + (j + pos % 3);
        f16x8 bfr[2];
#pragma unroll
        for (int nt = 0; nt < 2; nt++) {
            f16x8 x = *(const f16x8*)(act2h + ((size_t)(ip * 1024 + bbase + nt * 16 + n)) * 32 + quad * 8);
#pragma unroll
            for (int e = 0; e < 8; e++) {
                _Float16 v = x[e] * a8[e] + c8[e];
                x[e] = v > (_Float16)0.f ? v : (_Float16)0.f;
            }
            bfr[nt] = x;
        }
        f16x8 afr[4];
#pragma unroll
        for (int ot = 0; ot < 4; ot++)
            afr[ot] = *(const f16x8*)(W3h + ((size_t)((p * 9 + pos) * 64 + ot * 16 + n)) * 32 + quad * 8);
#pragma unroll
        for (int ot = 0; ot < 4; ot++)
#pragma unroll
            for (int nt = 0; nt < 2; nt++)
                acc[ot][nt] = __builtin_amdgcn_mfma_f32_16x16x32_f16(afr[ot], bfr[nt], acc[ot][nt], 0, 0, 0);
    }
    float s[16] = {}, q[16] = {};
#pragma unroll
    for (int ot = 0; ot < 4; ot++) {
        float bias[4];
#pragma unroll
        for (int r = 0; r < 4; r++) bias[r] = b3[(ot * 16 + quad * 4 + r) * 100 + p];
#pragma unroll
        for (int nt = 0; nt < 2; nt++) {
            int b = bbase + nt * 16 + n;
            f16x4 st;
#pragma unroll
            for (int r = 0; r < 4; r++) {
                float v = acc[ot][nt][r] + bias[r];
                st[r] = (_Float16)v;
                s[ot * 4 + r] += v; q[ot * 4 + r] += v * v;
            }
            *(f16x4*)(act3h + ((size_t)(p * 1024 + b)) * 64 + ot * 16 + quad * 4) = st;
        }
    }
    int w = (p * 8 + blockIdx.y) * 4 + wv;
#pragma unroll
    for (int u = 0; u < 16; u++) {
        float ss = s[u], qq = q[u];
#pragma unroll
        for (int d = 8; d; d >>= 1) { ss += __shfl_down(ss, d); qq += __shfl_down(qq, d); }
        if (n == 0) {
            int o = (u >> 2) * 16 + quad * 4 + (u & 3);
            part[(2 * o) * 3200 + w] = ss; part[(2 * o + 1) * 3200 + w] = qq;
        }
    }
}

// ---------------- FC: tanh(BN3(act3h)) @ fcW^T -> partials [p][jj][b] ----------------
__global__ __launch_bounds__(256) void k_fc(const _Float16* __restrict__ act3h,
                                            const float* __restrict__ fcW,
                                            const float* __restrict__ a3,
                                            const float* __restrict__ c3,
                                            float* __restrict__ fpart) {
    int p = blockIdx.y;
    int tid = threadIdx.x;
    int b = blockIdx.x * 256 + tid;
    __shared__ float wS[640], aS[64], cS[64];
    for (int idx = tid; idx < 640; idx += 256) {
        int o = idx / 10, jj = idx % 10;
        wS[idx] = fcW[jj * 6400 + o * 100 + p];
    }
    if (tid < 64) { aS[tid] = a3[tid]; cS[tid] = c3[tid]; }
    __syncthreads();
    float acc[10];
#pragma unroll
    for (int jj = 0; jj < 10; jj++) acc[jj] = 0.f;
    const _Float16* src = act3h + ((size_t)(p * 1024 + b)) * 64;
    for (int o8 = 0; o8 < 8; o8++) {
        f16x8 xv = *(const f16x8*)(src + o8 * 8);
#pragma unroll
        for (int e = 0; e < 8; e++) {
            int o = o8 * 8 + e;
            float v = fmaf(aS[o], (float)xv[e], cS[o]);
            float e2 = __expf(2.f * v);
            v = 1.f - 2.f / (e2 + 1.f);   // tanh, safe at +/-inf
#pragma unroll
            for (int jj = 0; jj < 10; jj++) acc[jj] = fmaf(wS[o * 10 + jj], v, acc[jj]);
        }
    }
#pragma unroll
    for (int jj = 0; jj < 10; jj++) fpart[((size_t)p * 10 + jj) * 1024 + b] = acc[jj];
}

// ---------------- reduce fc partials + bias -> out ----------------
__global__ __launch_bounds__(256) void k_fc_reduce(const float* __restrict__ fpart,
                                                   const float* __restrict__ fcb,
                                                   float* __restrict__ out) {
    int idx = blockIdx.x * 256 + threadIdx.x;  // jj*1024 + b
    int jj = idx >> 10, b = idx & 1023;
    float acc = fcb[jj];
    for (int p = 0; p < 100; p++) acc += fpart[(p * 10 + jj) * 1024 + b];
    out[b * 10 + jj] = acc;
}

extern "C" void kernel_launch(void* const* d_in, const int* in_sizes, int n_in,
                              void* d_out, int out_size, void* d_ws, size_t ws_size,
                              hipStream_t stream) {
    const float* x   = (const float*)d_in[0];
    const float* W1  = (const float*)d_in[1];
    const float* b1  = (const float*)d_in[2];
    const float* g1  = (const float*)d_in[3];
    const float* be1 = (const float*)d_in[4];
    const float* W2  = (const float*)d_in[5];
    const float* b2  = (const float*)d_in[6];
    const float* g2  = (const float*)d_in[7];
    const float* be2 = (const float*)d_in[8];
    const float* W3  = (const float*)d_in[9];
    const float* b3  = (const float*)d_in[10];
    const float* g3  = (const float*)d_in[11];
    const float* be3 = (const float*)d_in[12];
    const float* fcW = (const float*)d_in[13];
    const float* fcb = (const float*)d_in[14];
    float* out = (float*)d_out;
    float* ws = (float*)d_ws;

    float* xT    = ws + XT_OFF;
    _Float16* act1h = (_Float16*)(ws + ACT1_OFF);
    _Float16* act2h = (_Float16*)(ws + ACT2_OFF);
    _Float16* act3h = (_Float16*)(ws + ACT3_OFF);
    _Float16* W2h   = (_Float16*)(ws + W2H_OFF);
    _Float16* W3h   = (_Float16*)(ws + W3H_OFF);
    float* p1   = ws + P1_OFF;
    float* p2   = ws + P2_OFF;
    float* p3   = ws + P3_OFF;
    float* fp   = ws + FP_OFF;
    float* prm  = ws + PRM_OFF;
    _Float16* ach = (_Float16*)(ws + ACH_OFF);

    k_wcvt<<<10080, 256, 0, stream>>>(W2, W3, W2h, W3h);
    k_transpose<<<dim3(16, 64), dim3(16, 16), 0, stream>>>(x, xT);
    k_lc1<<<dim3(196, 4), 256, 0, stream>>>(xT, W1, b1, act1h, p1);
    k_stats<<<16, 256, 0, stream>>>(p1, 3136, g1, be1, prm, prm + 16, ach, 16, 1.f / (1024.f * 196.f));
    k_lc2m<<<dim3(144, 8), 256, 0, stream>>>(act1h, W2h, b2, ach, act2h, p2);
    k_stats<<<32, 256, 0, stream>>>(p2, 4608, g2, be2, prm + 32, prm + 64, ach + 32, 32, 1.f / (1024.f * 144.f));
    k_lc3m<<<dim3(100, 8), 256, 0, stream>>>(act2h, W3h, b3, ach + 32, act3h, p3);
    k_stats<<<64, 256, 0, stream>>>(p3, 3200, g3, be3, prm + 96, prm + 160, ach + 96, 64, 1.f / (1024.f * 100.f));
    k_fc<<<dim3(4, 100), 256, 0, stream>>>(act3h, fcW, prm + 96, prm + 160, fp);
    k_fc_reduce<<<40, 256, 0, stream>>>(fp, fcb, out);
}